// Round 3
// baseline (409.876 us; speedup 1.0000x reference)
//
#include <hip/hip_runtime.h>
#include <hip/hip_bf16.h>

// LinkPredictorGAT: out[e] = relu(concat(z[src[e]], z[dst[e]]) @ W1 + b1) @ W2 + b2
// z: [100000,256] f32, edges: [2,E] (int32 on device — harness converts int64->int32),
// W1: [512,128] f32, b1:[128], W2:[128,1], b2:[1]
// Strategy: pre-convert z and W1^T to bf16 in ws; fused MFMA GEMM+ReLU+GEMV.

typedef __attribute__((ext_vector_type(4))) float floatx4;
typedef __attribute__((ext_vector_type(8))) short short8;

#define BK 64
#define LDS_PAD 8

__device__ __forceinline__ unsigned short bf16rne(float x) {
    unsigned int u = __float_as_uint(x);
    u += 0x7fffu + ((u >> 16) & 1u);
    return (unsigned short)(u >> 16);
}

// ---- convert z (fp32 -> bf16), float4 per thread ----
__global__ void cvt_z(const float* __restrict__ z, unsigned short* __restrict__ zb, int n4) {
    int i = blockIdx.x * blockDim.x + threadIdx.x;
    if (i < n4) {
        float4 f = ((const float4*)z)[i];
        ushort4 u;
        u.x = bf16rne(f.x); u.y = bf16rne(f.y);
        u.z = bf16rne(f.z); u.w = bf16rne(f.w);
        ((ushort4*)zb)[i] = u;
    }
}

// ---- convert W1 [512][128] fp32 -> BT [128][512] bf16 (transposed) ----
__global__ void cvt_w1(const float* __restrict__ W1, unsigned short* __restrict__ BT) {
    int g = blockIdx.x * blockDim.x + threadIdx.x;   // 0..65535
    int k = g >> 7, n = g & 127;
    BT[n * 512 + k] = bf16rne(W1[g]);
}

// ---- fused gather + GEMM(512x128) + bias + relu + GEMV(W2) ----
// block = 256 threads (4 waves). M_TILE = 256 edges. Wave tile: 64 rows x 128 cols.
// A frags: direct global gather (bf16 or fp32 per template). B: LDS-staged BK=64 chunks.
template <bool ABF16>
__global__ __launch_bounds__(256, 2)
void fused_mlp(const float* __restrict__ zf, const unsigned short* __restrict__ zb,
               const int* __restrict__ eli, int E, int nnodes,
               const unsigned short* __restrict__ BT,
               const float* __restrict__ b1, const float* __restrict__ W2,
               const float* __restrict__ b2, float* __restrict__ out)
{
    __shared__ unsigned short btile[128][BK + LDS_PAD];   // +8: 2-way bank aliasing only (free)

    const int t = threadIdx.x;
    const int wid = t >> 6;
    const int lane = t & 63;
    const int l15 = lane & 15;
    const int quad = lane >> 4;
    const int m0 = blockIdx.x * 256;

    // node ids for this wave's 4 m-fragments (A-operand rows: m = lane&15)
    int src_id[4], dst_id[4];
#pragma unroll
    for (int mf = 0; mf < 4; ++mf) {
        int e = m0 + wid * 64 + mf * 16 + l15;
        e = e < E ? e : E - 1;                  // clamp tail (stores masked later)
        int s = eli[e];
        int d = eli[E + e];
        // safety clamp (indices are [0,nnodes) by construction)
        src_id[mf] = s < 0 ? 0 : (s >= nnodes ? nnodes - 1 : s);
        dst_id[mf] = d < 0 ? 0 : (d >= nnodes ? nnodes - 1 : d);
    }

    // epilogue constants: this lane's 8 columns
    float b1v[8], w2v[8];
#pragma unroll
    for (int nf = 0; nf < 8; ++nf) {
        int c = nf * 16 + l15;
        b1v[nf] = b1[c];
        w2v[nf] = W2[c];
    }

    floatx4 acc[4][8];
#pragma unroll
    for (int mf = 0; mf < 4; ++mf)
#pragma unroll
        for (int nf = 0; nf < 8; ++nf)
            acc[mf][nf] = (floatx4){0.f, 0.f, 0.f, 0.f};

    for (int kc = 0; kc < 8; ++kc) {           // 8 chunks of BK=64 over K=512
        const int k0 = kc * BK;
        __syncthreads();                        // prior chunk's reads done
        // stage B^T chunk: rows n=0..127, cols k0..k0+63 -> btile
#pragma unroll
        for (int p = 0; p < 4; ++p) {
            int flat = p * 256 + t;             // 0..1023 chunks of 8 bf16
            int n = flat >> 3;
            int c8 = (flat & 7) << 3;
            *(short8*)&btile[n][c8] = *(const short8*)(BT + n * 512 + k0 + c8);
        }
        __syncthreads();

#pragma unroll
        for (int ks = 0; ks < 2; ++ks) {        // two K=32 MFMA steps per chunk
            const int kk = k0 + ks * 32 + quad * 8;    // global k of this lane's 8 elems
            const bool use_src = (kk < 256);           // wave-uniform (k step=32 | 256)
            const int col = use_src ? kk : kk - 256;

            short8 a[4];
#pragma unroll
            for (int mf = 0; mf < 4; ++mf) {
                const int node = use_src ? src_id[mf] : dst_id[mf];
                if constexpr (ABF16) {
                    a[mf] = *(const short8*)(zb + ((long long)node << 8) + col);
                } else {
                    const float* pf = zf + ((long long)node << 8) + col;
                    float4 f0 = *(const float4*)pf;
                    float4 f1 = *(const float4*)(pf + 4);
                    short8 av;
                    av[0] = (short)bf16rne(f0.x); av[1] = (short)bf16rne(f0.y);
                    av[2] = (short)bf16rne(f0.z); av[3] = (short)bf16rne(f0.w);
                    av[4] = (short)bf16rne(f1.x); av[5] = (short)bf16rne(f1.y);
                    av[6] = (short)bf16rne(f1.z); av[7] = (short)bf16rne(f1.w);
                    a[mf] = av;
                }
            }
#pragma unroll
            for (int nf = 0; nf < 8; ++nf) {
                short8 b = *(const short8*)&btile[nf * 16 + l15][ks * 32 + quad * 8];
#pragma unroll
                for (int mf = 0; mf < 4; ++mf)
                    acc[mf][nf] = __builtin_amdgcn_mfma_f32_16x16x32_bf16(
                        a[mf], b, acc[mf][nf], 0, 0, 0);
            }
        }
    }

    // epilogue: h = relu(acc + b1); s = h . W2 ; reduce over 128 cols
    // C/D layout: col = lane&15 (+16*nf), row = quad*4 + r (+16*mf)
    const float b2s = b2[0];
#pragma unroll
    for (int mf = 0; mf < 4; ++mf) {
#pragma unroll
        for (int r = 0; r < 4; ++r) {
            float s = 0.f;
#pragma unroll
            for (int nf = 0; nf < 8; ++nf) {
                float v = acc[mf][nf][r] + b1v[nf];
                v = v > 0.f ? v : 0.f;
                s = fmaf(v, w2v[nf], s);
            }
            // sum across the 16 lanes holding different cols (xor<16 stays in quad group)
            s += __shfl_xor(s, 1);
            s += __shfl_xor(s, 2);
            s += __shfl_xor(s, 4);
            s += __shfl_xor(s, 8);
            if (l15 == 0) {
                int e = m0 + wid * 64 + mf * 16 + quad * 4 + r;
                if (e < E) out[e] = s + b2s;
            }
        }
    }
}

// ---- emergency fallback (tiny ws): one block per edge, fp32 vector ----
__global__ void naive_edge(const float* __restrict__ z, const int* __restrict__ eli,
                           int E, int nnodes,
                           const float* __restrict__ W1, const float* __restrict__ b1,
                           const float* __restrict__ W2, const float* __restrict__ b2,
                           float* __restrict__ out)
{
    __shared__ float red[2];
    int e = blockIdx.x;
    int j = threadIdx.x;                 // 0..127 -> hidden unit
    int s = eli[e], d = eli[E + e];
    s = s < 0 ? 0 : (s >= nnodes ? nnodes - 1 : s);
    d = d < 0 ? 0 : (d >= nnodes ? nnodes - 1 : d);
    const float* zs = z + (long long)s * 256;
    const float* zd = z + (long long)d * 256;
    float h = b1[j];
    for (int i = 0; i < 256; ++i) h = fmaf(zs[i], W1[i * 128 + j], h);
    for (int i = 0; i < 256; ++i) h = fmaf(zd[i], W1[(256 + i) * 128 + j], h);
    h = h > 0.f ? h : 0.f;
    float v = h * W2[j];
    v += __shfl_xor(v, 1);  v += __shfl_xor(v, 2);  v += __shfl_xor(v, 4);
    v += __shfl_xor(v, 8);  v += __shfl_xor(v, 16); v += __shfl_xor(v, 32);
    if ((threadIdx.x & 63) == 0) red[threadIdx.x >> 6] = v;
    __syncthreads();
    if (threadIdx.x == 0) out[e] = red[0] + red[1] + b2[0];
}

extern "C" void kernel_launch(void* const* d_in, const int* in_sizes, int n_in,
                              void* d_out, int out_size, void* d_ws, size_t ws_size,
                              hipStream_t stream) {
    const float* z   = (const float*)d_in[0];
    const int*   eli = (const int*)d_in[1];      // int64 in reference -> int32 on device
    const float* W1  = (const float*)d_in[2];
    const float* b1  = (const float*)d_in[3];
    const float* W2  = (const float*)d_in[4];
    const float* b2  = (const float*)d_in[5];
    float*       out = (float*)d_out;

    const int E      = in_sizes[1] / 2;
    const int nnodes = in_sizes[0] / 256;

    const size_t ZB  = (size_t)nnodes * 256 * 2;   // z in bf16
    const size_t BTB = (size_t)512 * 128 * 2;      // W1^T in bf16

    const int grid_main = (E + 255) / 256;

    if (ws_size >= ZB + BTB) {
        unsigned short* zb = (unsigned short*)d_ws;
        unsigned short* BT = (unsigned short*)((char*)d_ws + ZB);
        int n4 = nnodes * 64;  // float4 count
        cvt_z<<<(n4 + 255) / 256, 256, 0, stream>>>(z, zb, n4);
        cvt_w1<<<256, 256, 0, stream>>>(W1, BT);
        fused_mlp<true><<<grid_main, 256, 0, stream>>>(nullptr, zb, eli, E, nnodes, BT, b1, W2, b2, out);
    } else if (ws_size >= BTB) {
        unsigned short* BT = (unsigned short*)d_ws;
        cvt_w1<<<256, 256, 0, stream>>>(W1, BT);
        fused_mlp<false><<<grid_main, 256, 0, stream>>>(z, nullptr, eli, E, nnodes, BT, b1, W2, b2, out);
    } else {
        naive_edge<<<E, 128, 0, stream>>>(z, eli, E, nnodes, W1, b1, W2, b2, out);
    }
}